// Round 10
// baseline (752.275 us; speedup 1.0000x reference)
//
#include <hip/hip_runtime.h>
#include <hip/hip_bf16.h>

// CapsuleLayer dynamic routing, MI355X.
// Round 10: DIAGNOSTIC. Pipeline = r5 (330us) with W loads nontemporal (A/B
// for L3-pollution control). Appended copy_diag: EXACT uhat traffic (512MB
// fp32 read -> 256MB bf16 write) in perfect m13-copy shape (lane-contiguous
// both streams), 3 reps -> lands in profiler top-5 with counters. Decides
// "mixed-stream memory ceiling" vs "uhat consumption/store structure".

#define B_ 32
#define N_ 2048
#define D_ 32
#define C_ 64
#define V_ 32

typedef __attribute__((ext_vector_type(4))) float f32x4;
typedef __attribute__((ext_vector_type(4))) int i32x4;
typedef __attribute__((ext_vector_type(2))) int i32x2;
typedef __bf16 bf16x8 __attribute__((ext_vector_type(8)));

__device__ __forceinline__ unsigned f2bf1(float f) {
  unsigned u = __builtin_bit_cast(unsigned, f);
  return (u + 0x7FFFu + ((u >> 16) & 1u)) >> 16;  // RNE
}
__device__ __forceinline__ float bf2f(unsigned h) {
  unsigned u = h << 16;
  return __builtin_bit_cast(float, u);
}

// u_hat[n][b][p] (p=c*32+v), bf16. Block = one n, 4 waves; wave owns 512 p.
// 8 phases x 64 p: prefetch(ph+1, nontemporal) -> MFMA(ph) -> LDS buf[ph&1]
// -> lgkm fence -> dwordx4 flush.
__global__ __launch_bounds__(256) void uhat_kernel(const float* __restrict__ x,
                                                   const float* __restrict__ W,
                                                   unsigned short* __restrict__ uh) {
  const int n = blockIdx.x;
  const int wave = threadIdx.x >> 6;
  const int l = threadIdx.x & 63;
  const int l16 = l & 15, kg = l >> 4;  // A/B frag: row/col = l16, k = kg*8 + i

  __shared__ unsigned short lds[2][4][32 * 68];

  bf16x8 a[2];
#pragma unroll
  for (int mt = 0; mt < 2; ++mt) {
    const float* xp = x + (((size_t)(mt * 16 + l16)) * N_ + n) * D_ + kg * 8;
    f32x4 x0 = *(const f32x4*)xp;
    f32x4 x1 = *(const f32x4*)(xp + 4);
    i32x4 af;
    af[0] = f2bf1(x0[0]) | (f2bf1(x0[1]) << 16);
    af[1] = f2bf1(x0[2]) | (f2bf1(x0[3]) << 16);
    af[2] = f2bf1(x1[0]) | (f2bf1(x1[1]) << 16);
    af[3] = f2bf1(x1[2]) | (f2bf1(x1[3]) << 16);
    a[mt] = __builtin_bit_cast(bf16x8, af);
  }
  const f32x4 zero = {0.f, 0.f, 0.f, 0.f};
  const int br_f = l >> 1, half = l & 1;  // flush roles: 2 lanes per b-row
  const float* wbase = W + ((size_t)n * 2048 + wave * 512 + l16) * D_ + kg * 8;

  // prologue: load phase 0 into wreg (nontemporal: W is stream-once)
  f32x4 wreg[8];
#pragma unroll
  for (int pt4 = 0; pt4 < 4; ++pt4) {
    const f32x4* wp = (const f32x4*)(wbase + (size_t)(pt4 * 16) * D_);
    wreg[2 * pt4] = __builtin_nontemporal_load(wp);
    wreg[2 * pt4 + 1] = __builtin_nontemporal_load(wp + 1);
  }

#pragma unroll
  for (int ph = 0; ph < 8; ++ph) {
    unsigned short* wlds = lds[ph & 1][wave];
    // issue next phase's loads first: in flight across this phase's MFMA+flush
    f32x4 wnext[8];
    if (ph < 7) {
#pragma unroll
      for (int pt4 = 0; pt4 < 4; ++pt4) {
        const f32x4* wp = (const f32x4*)(wbase + (size_t)((ph + 1) * 64 + pt4 * 16) * D_);
        wnext[2 * pt4] = __builtin_nontemporal_load(wp);
        wnext[2 * pt4 + 1] = __builtin_nontemporal_load(wp + 1);
      }
      __builtin_amdgcn_sched_barrier(0);  // pin load issue above compute
    }
    // compute phase ph from wreg
#pragma unroll
    for (int pt4 = 0; pt4 < 4; ++pt4) {
      f32x4 w0 = wreg[2 * pt4], w1 = wreg[2 * pt4 + 1];
      i32x4 bv;
      bv[0] = f2bf1(w0[0]) | (f2bf1(w0[1]) << 16);
      bv[1] = f2bf1(w0[2]) | (f2bf1(w0[3]) << 16);
      bv[2] = f2bf1(w1[0]) | (f2bf1(w1[1]) << 16);
      bv[3] = f2bf1(w1[2]) | (f2bf1(w1[3]) << 16);
      bf16x8 bfrag = __builtin_bit_cast(bf16x8, bv);
#pragma unroll
      for (int mt = 0; mt < 2; ++mt) {
        f32x4 acc = __builtin_amdgcn_mfma_f32_16x16x32_bf16(a[mt], bfrag, zero, 0, 0, 0);
#pragma unroll
        for (int j = 0; j < 4; ++j) {
          const int br = mt * 16 + kg * 4 + j;  // C/D: row=(l>>4)*4+j, col=l&15
          wlds[br * 68 + pt4 * 16 + l16] = (unsigned short)f2bf1(acc[j]);
        }
      }
    }
    // this phase's LDS writes complete before cross-lane readback
    asm volatile("s_waitcnt lgkmcnt(0)" ::: "memory");
    __builtin_amdgcn_sched_barrier(0);
    {
      const unsigned short* src = wlds + br_f * 68 + half * 32;
      unsigned short* dst = uh + ((size_t)n * 32 + br_f) * 2048 +
                            (size_t)(wave * 512 + ph * 64 + half * 32);
      i32x4 v0 = *(const i32x4*)(src + 0);
      i32x4 v1 = *(const i32x4*)(src + 8);
      i32x4 v2 = *(const i32x4*)(src + 16);
      i32x4 v3 = *(const i32x4*)(src + 24);
      *(i32x4*)(dst + 0) = v0;
      *(i32x4*)(dst + 8) = v1;
      *(i32x4*)(dst + 16) = v2;
      *(i32x4*)(dst + 24) = v3;
    }
    __builtin_amdgcn_sched_barrier(0);  // keep flush ahead of next phase body
    if (ph < 7) {
#pragma unroll
      for (int i = 0; i < 8; ++i) wreg[i] = wnext[i];
    }
  }
}

// DIAGNOSTIC: uhat's exact traffic in perfect copy shape. Reads W (512MB) as
// lane-contiguous float4, converts to bf16, writes 256MB lane-contiguous to
// uh scratch (overwritten by next replay's uhat before any consumer). 3 reps.
__global__ __launch_bounds__(256) void copy_diag(const float* __restrict__ W,
                                                 unsigned short* __restrict__ dst) {
  const int tid = blockIdx.x * 256 + threadIdx.x;  // 524288 threads
  const f32x4* src = (const f32x4*)W;
#pragma unroll 1
  for (int rep = 0; rep < 3; ++rep) {
#pragma unroll 8
    for (int k = 0; k < 64; ++k) {
      f32x4 v = src[(size_t)k * 524288 + tid];
      i32x2 d;
      d[0] = (int)(f2bf1(v[0]) | (f2bf1(v[1]) << 16));
      d[1] = (int)(f2bf1(v[2]) | (f2bf1(v[3]) << 16));
      *(i32x2*)(dst + ((size_t)k * 524288 + tid) * 4) = d;
    }
  }
}

// Routing pass: s[b,c,v] = sum_n softmax_c(u_hat[b,n,:,:].vsum[b,:,:])[c] * u_hat[b,n,c,v]
// wave lane l == c. Block = 4 waves x 16 n, same b. Partials (no atomics) to ws.
template <int ROUND>
__global__ __launch_bounds__(256) void routing_kernel(const unsigned short* __restrict__ uh,
                                                      const float* __restrict__ vsum,
                                                      float* __restrict__ part) {
  const int b = blockIdx.x >> 5;  // 32 chunks per b
  const int chunk = blockIdx.x & 31;
  const int wave = threadIdx.x >> 6;
  const int l = threadIdx.x & 63;  // = c

  float vs[32];
  if (ROUND >= 2) {
    const f32x4* vp = (const f32x4*)(vsum + ((size_t)b * 64 + l) * 32);
#pragma unroll
    for (int i = 0; i < 8; ++i) {
      f32x4 t = vp[i];
      vs[4 * i] = t[0]; vs[4 * i + 1] = t[1]; vs[4 * i + 2] = t[2]; vs[4 * i + 3] = t[3];
    }
  }
  float sacc[32];
#pragma unroll
  for (int v = 0; v < 32; ++v) sacc[v] = 0.f;

  const int n0 = chunk * 64 + wave * 16;
  for (int ni = 0; ni < 16; ++ni) {
    const int n = n0 + ni;
    const i32x4* up = (const i32x4*)(uh + ((size_t)n * 32 + b) * 2048 + l * 32);
    i32x4 qs0 = up[0], qs1 = up[1], qs2 = up[2], qs3 = up[3];
    float u[32];
#pragma unroll
    for (int i = 0; i < 4; ++i) {
      unsigned v0 = (unsigned)qs0[i], v1 = (unsigned)qs1[i], v2 = (unsigned)qs2[i], v3 = (unsigned)qs3[i];
      u[0 + 2 * i] = bf2f(v0 & 0xffffu);  u[0 + 2 * i + 1] = bf2f(v0 >> 16);
      u[8 + 2 * i] = bf2f(v1 & 0xffffu);  u[8 + 2 * i + 1] = bf2f(v1 >> 16);
      u[16 + 2 * i] = bf2f(v2 & 0xffffu); u[16 + 2 * i + 1] = bf2f(v2 >> 16);
      u[24 + 2 * i] = bf2f(v3 & 0xffffu); u[24 + 2 * i + 1] = bf2f(v3 >> 16);
    }
    float r;
    if (ROUND >= 2) {
      float br = 0.f;
#pragma unroll
      for (int v = 0; v < 32; ++v) br = fmaf(u[v], vs[v], br);
      float m = br;
#pragma unroll
      for (int off = 32; off; off >>= 1) m = fmaxf(m, __shfl_xor(m, off, 64));
      float e = __expf(br - m);
      float den = e;
#pragma unroll
      for (int off = 32; off; off >>= 1) den += __shfl_xor(den, off, 64);
      r = e / den;
    } else {
      r = 1.0f / 64.0f;  // softmax of zeros
    }
#pragma unroll
    for (int v = 0; v < 32; ++v) sacc[v] = fmaf(r, u[v], sacc[v]);
  }

  __shared__ float red[4][64][33];  // +1 pad: conflict-free
#pragma unroll
  for (int v = 0; v < 32; ++v) red[wave][l][v] = sacc[v];
  __syncthreads();
  const int t = threadIdx.x;
  f32x4 o0, o1;
#pragma unroll
  for (int i = 0; i < 4; ++i) {
    const int e0 = t * 8 + i, e1 = t * 8 + 4 + i;
    o0[i] = red[0][e0 >> 5][e0 & 31] + red[1][e0 >> 5][e0 & 31] +
            red[2][e0 >> 5][e0 & 31] + red[3][e0 >> 5][e0 & 31];
    o1[i] = red[0][e1 >> 5][e1 & 31] + red[1][e1 >> 5][e1 & 31] +
            red[2][e1 >> 5][e1 & 31] + red[3][e1 >> 5][e1 & 31];
  }
  float* pp = part + ((size_t)blockIdx.x) * 2048 + t * 8;
  *(f32x4*)pp = o0;
  *(f32x4*)(pp + 4) = o1;
}

// Reduce partials -> s, squash -> v. Writes v to out; maintains vsum for agreement.
template <int ROUND>
__global__ __launch_bounds__(256) void squash_kernel(const float* __restrict__ part,
                                                     float* __restrict__ vsum,
                                                     float* __restrict__ out) {
  const int t = blockIdx.x * 256 + threadIdx.x;  // 0..65535 = b*2048 + c*32 + v
  const int b = t >> 11;
  const int e = t & 2047;
  float sv = 0.f;
#pragma unroll
  for (int k = 0; k < 32; ++k) sv += part[((size_t)(b * 32 + k)) * 2048 + e];
  float sq = sv * sv;
#pragma unroll
  for (int off = 16; off; off >>= 1) sq += __shfl_xor(sq, off, 64);  // sum over v (32-lane groups)
  float scale = (sq / (1.f + sq)) * rsqrtf(sq + 1e-9f);
  float val = sv * scale;
  out[t] = val;
  if (ROUND == 1) vsum[t] = val;
  else if (ROUND == 2) vsum[t] += val;
}

extern "C" void kernel_launch(void* const* d_in, const int* in_sizes, int n_in,
                              void* d_out, int out_size, void* d_ws, size_t ws_size,
                              hipStream_t stream) {
  const float* x = (const float*)d_in[0];  // [B,N,D]
  const float* W = (const float*)d_in[1];  // [1,N,C,V,D]
  float* out = (float*)d_out;              // [B,1,C,V,1] = 65536 fp32

  const size_t UH_BYTES = (size_t)B_ * N_ * C_ * V_ * 2;  // 268435456
  const size_t PART_BYTES = (size_t)B_ * 32 * 2048 * 4;   // 8388608
  const size_t VSUM_BYTES = (size_t)B_ * C_ * V_ * 4;     // 262144
  if (ws_size < UH_BYTES + PART_BYTES + VSUM_BYTES) return;  // can't run

  unsigned short* uh = (unsigned short*)d_ws;
  float* part = (float*)((char*)d_ws + UH_BYTES);
  float* vsum = (float*)((char*)d_ws + UH_BYTES + PART_BYTES);

  uhat_kernel<<<N_, 256, 0, stream>>>(x, W, uh);
  routing_kernel<1><<<B_ * 32, 256, 0, stream>>>(uh, vsum, part);
  squash_kernel<1><<<256, 256, 0, stream>>>(part, vsum, out);
  routing_kernel<2><<<B_ * 32, 256, 0, stream>>>(uh, vsum, part);
  squash_kernel<2><<<256, 256, 0, stream>>>(part, vsum, out);
  routing_kernel<3><<<B_ * 32, 256, 0, stream>>>(uh, vsum, part);
  squash_kernel<3><<<256, 256, 0, stream>>>(part, vsum, out);
  // diagnostic last: uh is scratch here, fully rewritten by next replay's uhat
  copy_diag<<<N_, 256, 0, stream>>>(W, uh);
}

// Round 11
// 305.419 us; speedup vs baseline: 2.4631x; 2.4631x over previous
//
#include <hip/hip_runtime.h>
#include <hip/hip_bf16.h>

// CapsuleLayer dynamic routing, MI355X.
// B=32,N=2048,D=32 inputs; C=64,V=32 output caps; 3 routing rounds.
// u_hat (bf16 [n][b][p], 256MB ws) via MFMA; 3 fused routing passes using
// agreement linearity (b_logits = u_hat.(v1+v2+...)).
// Round 11: BOTH uhat streams dense. r10's copy_diag proved the memory system
// moves uhat's exact traffic in 148us when both streams are lane-contiguous;
// r5/r7/r9 showed fixing only one stream is neutral (either scattered stream
// saturates L2 request rate: scattered = 2-4x lines touched per KB). This
// kernel: r9's verified dense read path (global_load_lds 1KB/instr, XOR-
// swizzled, counted vmcnt) + LDS out-staging [32b][64p] flushed every 2
// sub-phases as 4 dense-equivalent stores (8 rows x 128B = 16 full lines
// per instr). Layout [n][b][p] keeps routing at its proven 34us/round.

#define B_ 32
#define N_ 2048
#define D_ 32
#define C_ 64
#define V_ 32

typedef __attribute__((ext_vector_type(4))) float f32x4;
typedef __attribute__((ext_vector_type(4))) int i32x4;
typedef __attribute__((ext_vector_type(2))) int i32x2;
typedef __bf16 bf16x8 __attribute__((ext_vector_type(8)));

__device__ __forceinline__ unsigned f2bf1(float f) {
  unsigned u = __builtin_bit_cast(unsigned, f);
  return (u + 0x7FFFu + ((u >> 16) & 1u)) >> 16;  // RNE
}
__device__ __forceinline__ float bf2f(unsigned h) {
  unsigned u = h << 16;
  return __builtin_bit_cast(float, u);
}

__device__ __forceinline__ bf16x8 cvt_frag(f32x4 lo, f32x4 hi) {
  i32x4 r;
  r[0] = f2bf1(lo[0]) | (f2bf1(lo[1]) << 16);
  r[1] = f2bf1(lo[2]) | (f2bf1(lo[3]) << 16);
  r[2] = f2bf1(hi[0]) | (f2bf1(hi[1]) << 16);
  r[3] = f2bf1(hi[2]) | (f2bf1(hi[3]) << 16);
  return __builtin_bit_cast(bf16x8, r);
}

__device__ __forceinline__ void gload16(const float* g, float* l) {
  __builtin_amdgcn_global_load_lds(
      (const __attribute__((address_space(1))) void*)g,
      (__attribute__((address_space(3))) void*)l, 16, 0, 0);
}

// u_hat[n][b][p], bf16. Block = one n, 4 waves; wave owns 512 p-rows.
// 16 sub-phases x 32 rows: dense-staged W (r9 machinery) -> 2 ptile MFMAs ->
// 8B ds_writes into [32b][64p] out tile (72-short stride, bank-minimal) ->
// every 2nd sub-phase flush 4KB as 4 dense store instrs (8 rows x 128B each).
__global__ __launch_bounds__(256) void uhat_kernel(const float* __restrict__ x,
                                                   const float* __restrict__ W,
                                                   unsigned short* __restrict__ uh) {
  const int n = blockIdx.x;
  const int wave = threadIdx.x >> 6;
  const int l = threadIdx.x & 63;
  const int l16 = l & 15, kg = l >> 4;    // fragment roles
  const int lrow = l >> 3, lcol = l & 7;  // staging roles (8 rows x 8 slots)

  __shared__ float wlds[4][2][1024];          // 32KB: W chunks, dbuf
  __shared__ unsigned short olds[4][32 * 72];  // 18KB: out tiles
  float* wbuf0 = &wlds[wave][0][0];
  float* wbuf1 = &wlds[wave][1][0];
  unsigned short* obuf = &olds[wave][0];

  // B-operand = x: lane l16 = col b (+16 per bt), k = kg*8..+7
  bf16x8 xb[2];
#pragma unroll
  for (int bt = 0; bt < 2; ++bt) {
    const float* xp = x + (((size_t)(bt * 16 + l16)) * N_ + n) * D_ + kg * 8;
    xb[bt] = cvt_frag(*(const f32x4*)xp, *(const f32x4*)(xp + 4));
  }
  __builtin_amdgcn_sched_barrier(0);

  const f32x4 zero = {0.f, 0.f, 0.f, 0.f};
  // dense staging source with inverse swizzle (r9-verified)
  const int src_off_f = lrow * 32 + (((lcol * 16) ^ (lrow << 4)) >> 2);
  const float* wsrc = W + (size_t)n * 65536 + (size_t)wave * 16384 + src_off_f;
  unsigned short* ubase = uh + (size_t)n * 65536 + wave * 512;  // + b*2048 + p
  const unsigned char* rb0 = (const unsigned char*)wbuf0;
  const unsigned char* rb1 = (const unsigned char*)wbuf1;
  const int a_base = (kg * 32) ^ ((l16 & 7) << 4);  // swizzled frag col

  // prologue: stage sub-phase 0
#pragma unroll
  for (int s = 0; s < 4; ++s) gload16(wsrc + s * 256, wbuf0 + s * 256);

#pragma unroll
  for (int ph = 0; ph < 16; ++ph) {
    if (ph < 15) {
      const float* ws = wsrc + (size_t)(ph + 1) * 1024;
      float* dbuf = ((ph + 1) & 1) ? wbuf1 : wbuf0;
#pragma unroll
      for (int s = 0; s < 4; ++s) gload16(ws + s * 256, dbuf + s * 256);
      asm volatile("s_waitcnt vmcnt(4)" ::: "memory");
    } else {
      asm volatile("s_waitcnt vmcnt(0)" ::: "memory");
    }
    __builtin_amdgcn_sched_barrier(0);
    const unsigned char* rb = (ph & 1) ? rb1 : rb0;
#pragma unroll
    for (int t = 0; t < 2; ++t) {
      const int a0 = (t * 16 + l16) * 128 + a_base;
      f32x4 lo = *(const f32x4*)(rb + a0);
      f32x4 hi = *(const f32x4*)(rb + (a0 ^ 16));
      bf16x8 wfrag = cvt_frag(lo, hi);
#pragma unroll
      for (int bt = 0; bt < 2; ++bt) {
        f32x4 acc = __builtin_amdgcn_mfma_f32_16x16x32_bf16(wfrag, xb[bt], zero, 0, 0, 0);
        i32x2 dv;
        dv[0] = (int)(f2bf1(acc[0]) | (f2bf1(acc[1]) << 16));
        dv[1] = (int)(f2bf1(acc[2]) | (f2bf1(acc[3]) << 16));
        // out tile: row b = bt*16+l16 (stride 72), p_local = (ph&1)*32+t*16+kg*4
        *(i32x2*)(obuf + (bt * 16 + l16) * 72 + (ph & 1) * 32 + t * 16 + kg * 4) = dv;
      }
    }
    if (ph & 1) {
      // out-tile writes (cross-lane) visible before gather
      asm volatile("s_waitcnt lgkmcnt(0)" ::: "memory");
      __builtin_amdgcn_sched_barrier(0);
      const int pbase = (ph >> 1) * 64;  // 0..448
#pragma unroll
      for (int i = 0; i < 4; ++i) {
        const int b = i * 8 + (l >> 3);
        const unsigned short* s = obuf + b * 72 + (l & 7) * 8;
        i32x4 v = *(const i32x4*)s;
        *(i32x4*)(ubase + (size_t)b * 2048 + pbase + (l & 7) * 8) = v;
      }
      // compiler waits lgkm before stores consume v -> reads done ->
      // next sub-phase's ds_writes are WAR-safe without extra fence
    }
  }
}

// Routing pass: s[b,c,v] = sum_n softmax_c(u_hat[b,n,:,:].vsum[b,:,:])[c] * u_hat[b,n,c,v]
// wave lane l == c. Block = 4 waves x 16 n, same b. Partials (no atomics) to ws.
template <int ROUND>
__global__ __launch_bounds__(256) void routing_kernel(const unsigned short* __restrict__ uh,
                                                      const float* __restrict__ vsum,
                                                      float* __restrict__ part) {
  const int b = blockIdx.x >> 5;  // 32 chunks per b
  const int chunk = blockIdx.x & 31;
  const int wave = threadIdx.x >> 6;
  const int l = threadIdx.x & 63;  // = c

  float vs[32];
  if (ROUND >= 2) {
    const f32x4* vp = (const f32x4*)(vsum + ((size_t)b * 64 + l) * 32);
#pragma unroll
    for (int i = 0; i < 8; ++i) {
      f32x4 t = vp[i];
      vs[4 * i] = t[0]; vs[4 * i + 1] = t[1]; vs[4 * i + 2] = t[2]; vs[4 * i + 3] = t[3];
    }
  }
  float sacc[32];
#pragma unroll
  for (int v = 0; v < 32; ++v) sacc[v] = 0.f;

  const int n0 = chunk * 64 + wave * 16;
  for (int ni = 0; ni < 16; ++ni) {
    const int n = n0 + ni;
    const i32x4* up = (const i32x4*)(uh + ((size_t)n * 32 + b) * 2048 + l * 32);
    i32x4 qs0 = up[0], qs1 = up[1], qs2 = up[2], qs3 = up[3];
    float u[32];
#pragma unroll
    for (int i = 0; i < 4; ++i) {
      unsigned v0 = (unsigned)qs0[i], v1 = (unsigned)qs1[i], v2 = (unsigned)qs2[i], v3 = (unsigned)qs3[i];
      u[0 + 2 * i] = bf2f(v0 & 0xffffu);  u[0 + 2 * i + 1] = bf2f(v0 >> 16);
      u[8 + 2 * i] = bf2f(v1 & 0xffffu);  u[8 + 2 * i + 1] = bf2f(v1 >> 16);
      u[16 + 2 * i] = bf2f(v2 & 0xffffu); u[16 + 2 * i + 1] = bf2f(v2 >> 16);
      u[24 + 2 * i] = bf2f(v3 & 0xffffu); u[24 + 2 * i + 1] = bf2f(v3 >> 16);
    }
    float r;
    if (ROUND >= 2) {
      float br = 0.f;
#pragma unroll
      for (int v = 0; v < 32; ++v) br = fmaf(u[v], vs[v], br);
      float m = br;
#pragma unroll
      for (int off = 32; off; off >>= 1) m = fmaxf(m, __shfl_xor(m, off, 64));
      float e = __expf(br - m);
      float den = e;
#pragma unroll
      for (int off = 32; off; off >>= 1) den += __shfl_xor(den, off, 64);
      r = e / den;
    } else {
      r = 1.0f / 64.0f;  // softmax of zeros
    }
#pragma unroll
    for (int v = 0; v < 32; ++v) sacc[v] = fmaf(r, u[v], sacc[v]);
  }

  __shared__ float red[4][64][33];  // +1 pad: conflict-free
#pragma unroll
  for (int v = 0; v < 32; ++v) red[wave][l][v] = sacc[v];
  __syncthreads();
  const int t = threadIdx.x;
  f32x4 o0, o1;
#pragma unroll
  for (int i = 0; i < 4; ++i) {
    const int e0 = t * 8 + i, e1 = t * 8 + 4 + i;
    o0[i] = red[0][e0 >> 5][e0 & 31] + red[1][e0 >> 5][e0 & 31] +
            red[2][e0 >> 5][e0 & 31] + red[3][e0 >> 5][e0 & 31];
    o1[i] = red[0][e1 >> 5][e1 & 31] + red[1][e1 >> 5][e1 & 31] +
            red[2][e1 >> 5][e1 & 31] + red[3][e1 >> 5][e1 & 31];
  }
  float* pp = part + ((size_t)blockIdx.x) * 2048 + t * 8;
  *(f32x4*)pp = o0;
  *(f32x4*)(pp + 4) = o1;
}

// Reduce partials -> s, squash -> v. Writes v to out; maintains vsum for agreement.
template <int ROUND>
__global__ __launch_bounds__(256) void squash_kernel(const float* __restrict__ part,
                                                     float* __restrict__ vsum,
                                                     float* __restrict__ out) {
  const int t = blockIdx.x * 256 + threadIdx.x;  // 0..65535 = b*2048 + c*32 + v
  const int b = t >> 11;
  const int e = t & 2047;
  float sv = 0.f;
#pragma unroll
  for (int k = 0; k < 32; ++k) sv += part[((size_t)(b * 32 + k)) * 2048 + e];
  float sq = sv * sv;
#pragma unroll
  for (int off = 16; off; off >>= 1) sq += __shfl_xor(sq, off, 64);  // sum over v (32-lane groups)
  float scale = (sq / (1.f + sq)) * rsqrtf(sq + 1e-9f);
  float val = sv * scale;
  out[t] = val;
  if (ROUND == 1) vsum[t] = val;
  else if (ROUND == 2) vsum[t] += val;
}

extern "C" void kernel_launch(void* const* d_in, const int* in_sizes, int n_in,
                              void* d_out, int out_size, void* d_ws, size_t ws_size,
                              hipStream_t stream) {
  const float* x = (const float*)d_in[0];  // [B,N,D]
  const float* W = (const float*)d_in[1];  // [1,N,C,V,D]
  float* out = (float*)d_out;              // [B,1,C,V,1] = 65536 fp32

  const size_t UH_BYTES = (size_t)B_ * N_ * C_ * V_ * 2;  // 268435456
  const size_t PART_BYTES = (size_t)B_ * 32 * 2048 * 4;   // 8388608
  const size_t VSUM_BYTES = (size_t)B_ * C_ * V_ * 4;     // 262144
  if (ws_size < UH_BYTES + PART_BYTES + VSUM_BYTES) return;  // can't run

  unsigned short* uh = (unsigned short*)d_ws;
  float* part = (float*)((char*)d_ws + UH_BYTES);
  float* vsum = (float*)((char*)d_ws + UH_BYTES + PART_BYTES);

  uhat_kernel<<<N_, 256, 0, stream>>>(x, W, uh);
  routing_kernel<1><<<B_ * 32, 256, 0, stream>>>(uh, vsum, part);
  squash_kernel<1><<<256, 256, 0, stream>>>(part, vsum, out);
  routing_kernel<2><<<B_ * 32, 256, 0, stream>>>(uh, vsum, part);
  squash_kernel<2><<<256, 256, 0, stream>>>(part, vsum, out);
  routing_kernel<3><<<B_ * 32, 256, 0, stream>>>(uh, vsum, part);
  squash_kernel<3><<<256, 256, 0, stream>>>(part, vsum, out);
}